// Round 1
// baseline (847.701 us; speedup 1.0000x reference)
//
#include <hip/hip_runtime.h>
#include <math.h>

#define NN 50000
#define HH 128
#define KK 8

// ws float offsets
#define WS_WTF  0         // [Of;Zf] transposed bf16: wtf[c*256+k], 32768 shorts = 16384 fslots
#define WS_BT   16384     // stacked B transposed bf16: bt[c*384+k], 147456 shorts = 73728 fslots
#define WS_KV   90112     // 128x128 f32 Kf@vf
#define WS_T0   106496    // 128x128 f32 KV@Wd
#define WS_T1   122880    // 128x128 f32 KV@Wa
#define WS_kv   139264    // 128 f32 Kf@Vf
#define WS_qv   139392    // 128 f32 Qf@Vf
// end 139520 floats = 558 KB

typedef __attribute__((ext_vector_type(8))) unsigned short u16x8;
typedef __attribute__((ext_vector_type(8))) __bf16 bf16x8;
typedef __attribute__((ext_vector_type(4))) float f32x4;
union Frag { u16x8 u; bf16x8 b; };

__device__ __forceinline__ unsigned short f2bf(float f) {
    unsigned u = __builtin_bit_cast(unsigned, f);
    u += 0x7fffu + ((u >> 16) & 1u);
    return (unsigned short)(u >> 16);
}
__device__ __forceinline__ float sigm(float v) { return 1.f / (1.f + expf(-v)); }

// ---- prep kernels ----
// prepA = prep1 (KV, kv, qv, Wiou pack) + prep4 (WtF pack) merged: 98560 tasks
__global__ void prepA(const float* __restrict__ Kf, const float* __restrict__ Qf,
                      const float* __restrict__ vf, const float* __restrict__ Vf,
                      const float* __restrict__ Wiou, const float* __restrict__ Of,
                      const float* __restrict__ Zf, float* __restrict__ ws) {
    int idx = blockIdx.x * 256 + threadIdx.x;   // 385 blocks * 256 = 98560 exact
    unsigned short* bt = (unsigned short*)(ws + WS_BT);
    if (idx < 16384) {
        int a = idx >> 7, c = idx & 127;
        float s = 0.f;
        for (int b = 0; b < 128; ++b) s += Kf[a * 128 + b] * vf[b * 128 + c];
        ws[WS_KV + idx] = s;
    } else if (idx < 16512) {
        int a = idx - 16384;
        float s = 0.f;
        for (int b = 0; b < 128; ++b) s += Kf[a * 128 + b] * Vf[b];
        ws[WS_kv + a] = s;
    } else if (idx < 16640) {
        int a = idx - 16512;
        float s = 0.f;
        for (int b = 0; b < 128; ++b) s += Qf[a * 128 + b] * Vf[b];
        ws[WS_qv + a] = s;
    } else if (idx < 65792) {
        int i = idx - 16640;                     // < 49152; Wiou rows 0..127 of B
        int r = i / 384, c = i % 384;
        bt[c * 384 + r] = f2bf(Wiou[i]);
    } else {
        int i = idx - 65792;                     // < 32768: wtf[c*256+k]
        int c = i >> 8, k = i & 255;
        float v = (k < 128) ? Of[k * 128 + c] : Zf[(k - 128) * 128 + c];
        unsigned short* wtf = (unsigned short*)(ws + WS_WTF);
        wtf[i] = f2bf(v);
    }
}

__global__ void prep2(const float* __restrict__ Wd, const float* __restrict__ Wa,
                      float* __restrict__ ws) {
    int idx = blockIdx.x * 256 + threadIdx.x;   // 32768 tasks
    int sel = idx >> 14;
    int r = (idx >> 7) & 127, c = idx & 127;
    const float* W = sel ? Wa : Wd;
    const float* Kv = ws + WS_KV;
    float s = 0.f;
    for (int h = 0; h < 128; ++h) s += Kv[r * 128 + h] * W[h * 128 + c];
    ws[(sel ? WS_T1 : WS_T0) + r * 128 + c] = s;
}

__global__ void prep3(const float* __restrict__ Uiou, float* __restrict__ ws) {
    int idx = blockIdx.x * 256 + threadIdx.x;   // 98304 tasks
    int half = (idx >= 49152) ? 1 : 0;
    int i2 = idx - half * 49152;
    int r = i2 / 384, c = i2 % 384;
    const float* T = ws + (half ? WS_T1 : WS_T0);
    const float* U = Uiou + half * 128 * 384;
    float s = 0.f;
    for (int h = 0; h < 128; ++h) s += T[r * 128 + h] * U[h * 384 + c];
    unsigned short* bt = (unsigned short*)(ws + WS_BT);
    bt[c * 384 + (128 + half * 128 + r)] = f2bf(s);   // B row = 128+half*128+r, transposed store
}

// ---- main fused kernel: 16 nodes / block, 256 threads ----
// LDS: GfS 12288 + credS 8448 + efS 512 + kvqS 1024 = 22272 B -> 4 blocks/CU (VGPR-capped)
__global__ __launch_bounds__(256, 4) void tree_main(
    const float* __restrict__ x, const float* __restrict__ h_mail,
    const float* __restrict__ c_mail, const float* __restrict__ biou,
    const int* __restrict__ etype, const float* __restrict__ ws,
    float* __restrict__ out)
{
    // G in MFMA-fragment order: GfS[(col>>3)*128 + node*8 + (col&7)], bf16
    __shared__ unsigned short GfS[48 * 128];     // 12288 B
    __shared__ float credS[16 * 132];            // 8448 B, stride 132: 2-way bank max
    __shared__ float efS[128];
    __shared__ float kvqS[256];

    const int t = threadIdx.x;
    const int node0 = blockIdx.x * 16;

    // ---------- phase A: attention coefficients + G build ----------
    {
        const int n = t >> 4, s = t & 15, c0 = s * 8;
        const int node = node0 + n;
        kvqS[t] = ws[WS_kv + t];                 // kv | qv contiguous
        if (t < 128) efS[t] = (float)etype[node0 * KK + t];

        float xv[8];
        const float4* xp = (const float4*)(x + node * HH + c0);
        float4 x0 = xp[0], x1 = xp[1];
        xv[0]=x0.x; xv[1]=x0.y; xv[2]=x0.z; xv[3]=x0.w;
        xv[4]=x1.x; xv[5]=x1.y; xv[6]=x1.z; xv[7]=x1.w;
        u16x8 xg;
        #pragma unroll
        for (int j = 0; j < 8; ++j) xg[j] = f2bf(xv[j]);
        *(u16x8*)(&GfS[s * 128 + n * 8]) = xg;   // cols 0..127 (col>>3 == s)
        __syncthreads();

        float xq = 0.f;
        #pragma unroll
        for (int j = 0; j < 8; ++j) xq += xv[j] * kvqS[128 + c0 + j];

        // read h_mail ONCE: keep 8x8 values in registers across the softmax
        float hv[KK][8];
        float p[KK];
        #pragma unroll
        for (int k = 0; k < KK; ++k) {
            const float4* hp = (const float4*)(h_mail + (node * KK + k) * HH + c0);
            float4 h0 = hp[0], h1 = hp[1];
            hv[k][0]=h0.x; hv[k][1]=h0.y; hv[k][2]=h0.z; hv[k][3]=h0.w;
            hv[k][4]=h1.x; hv[k][5]=h1.y; hv[k][6]=h1.z; hv[k][7]=h1.w;
            float pk = 0.f;
            #pragma unroll
            for (int j = 0; j < 8; ++j) pk += hv[k][j] * kvqS[c0 + j];
            p[k] = pk;
        }
        #pragma unroll
        for (int msk = 8; msk >= 1; msk >>= 1) {
            xq += __shfl_xor(xq, msk, 16);
            #pragma unroll
            for (int k = 0; k < KK; ++k) p[k] += __shfl_xor(p[k], msk, 16);
        }
        float ef[KK], esum = 0.f;
        #pragma unroll
        for (int k = 0; k < KK; ++k) { ef[k] = efS[n * KK + k]; esum += ef[k]; }
        const float mod = esum * 0.125f;
        const float sa = 1.f - mod, sb = mod;

        float tk[KK], mx = -1e30f;
        #pragma unroll
        for (int k = 0; k < KK; ++k) { tk[k] = tanhf(xq + p[k]); mx = fmaxf(mx, tk[k]); }
        float wsum = 0.f;
        #pragma unroll
        for (int k = 0; k < KK; ++k) { tk[k] = expf(tk[k] - mx); wsum += tk[k]; }
        const float inv = 1.f / wsum;
        float a0[8] = {0,0,0,0,0,0,0,0}, a1[8] = {0,0,0,0,0,0,0,0};
        #pragma unroll
        for (int k = 0; k < KK; ++k) {
            float w = tk[k] * inv;
            const float cf0 = sb * w * (1.f - ef[k]);
            const float cf1 = sa * w * ef[k];
            #pragma unroll
            for (int j = 0; j < 8; ++j) { a0[j] += cf0 * hv[k][j]; a1[j] += cf1 * hv[k][j]; }
        }
        u16x8 g0, g1;
        #pragma unroll
        for (int j = 0; j < 8; ++j) { g0[j] = f2bf(a0[j]); g1[j] = f2bf(a1[j]); }
        *(u16x8*)(&GfS[(16 + s) * 128 + n * 8]) = g0;   // cols 128..255
        *(u16x8*)(&GfS[(32 + s) * 128 + n * 8]) = g1;   // cols 256..383
    }
    __syncthreads();

    // ---------- phase B: F-GEMM (K-doubled) + cred ----------
    const int wave = t >> 6, lane = t & 63, m = lane & 15, q = lane >> 4;
    {
        const unsigned short* WtF = (const unsigned short*)(ws + WS_WTF);
        f32x4 acc[2][8];
        #pragma unroll
        for (int rt = 0; rt < 2; ++rt)
            #pragma unroll
            for (int tc = 0; tc < 8; ++tc) acc[rt][tc] = (f32x4){0.f,0.f,0.f,0.f};

        #pragma unroll
        for (int ks = 0; ks < 8; ++ks) {
            const int kg = ks * 32 + q * 8;          // 0..255
            Frag bf[8], af[2];
            #pragma unroll
            for (int tc = 0; tc < 8; ++tc)
                bf[tc].u = *(const u16x8*)(WtF + (tc * 16 + m) * 256 + kg);
            #pragma unroll
            for (int rt = 0; rt < 2; ++rt) {
                const int r = wave * 32 + rt * 16 + m;
                const float msk = (ks < 4) ? efS[r] : (1.f - efS[r]);
                const float4* hp = (const float4*)(h_mail + (node0 * KK + r) * HH + (kg & 127));
                float4 h0 = hp[0], h1 = hp[1];
                float tv[8];
                tv[0]=h0.x*msk; tv[1]=h0.y*msk; tv[2]=h0.z*msk; tv[3]=h0.w*msk;
                tv[4]=h1.x*msk; tv[5]=h1.y*msk; tv[6]=h1.z*msk; tv[7]=h1.w*msk;
                #pragma unroll
                for (int j = 0; j < 8; ++j) af[rt].u[j] = f2bf(tv[j]);
            }
            #pragma unroll
            for (int rt = 0; rt < 2; ++rt)
                #pragma unroll
                for (int tc = 0; tc < 8; ++tc)
                    acc[rt][tc] = __builtin_amdgcn_mfma_f32_16x16x32_bf16(
                        af[rt].b, bf[tc].b, acc[rt][tc], 0, 0, 0);
        }
        // cred: sigmoid(F) * c_mail, summed over k (8 rows per node)
        // c_mail loads hoisted per rt: 32 independent dword loads off one base,
        // all offsets immediate-foldable (<= 1984 B) -> they pipeline as one batch
        #pragma unroll
        for (int rt = 0; rt < 2; ++rt) {
            const int rbase = wave * 32 + rt * 16;
            const float* cp = c_mail + (node0 * KK + rbase + q * 4) * HH + m;
            float cm[8][4];
            #pragma unroll
            for (int tc = 0; tc < 8; ++tc)
                #pragma unroll
                for (int reg = 0; reg < 4; ++reg)
                    cm[tc][reg] = cp[reg * HH + tc * 16];
            #pragma unroll
            for (int tc = 0; tc < 8; ++tc) {
                float sacc = 0.f;
                #pragma unroll
                for (int reg = 0; reg < 4; ++reg)
                    sacc += sigm(acc[rt][tc][reg]) * cm[tc][reg];
                sacc += __shfl_xor(sacc, 16);
                if ((q & 1) == 0) {
                    const int nl = (rbase >> 3) + (q >> 1);
                    credS[nl * 132 + tc * 16 + m] = sacc;
                }
            }
        }
    }

    // ---------- phase C: iou = G @ B (K=384), col-triple assignment ----------
    // wave w owns col-tiles {2w,2w+1, 8+2w,8+2w+1, 16+2w,16+2w+1} so its
    // accumulators hold matching (i,o,u) for cols [32w,32w+32) -> epilogue in regs
    f32x4 acc2[6];
    {
        const unsigned short* Bt = (const unsigned short*)(ws + WS_BT);
        #pragma unroll
        for (int j = 0; j < 6; ++j) acc2[j] = (f32x4){0.f,0.f,0.f,0.f};
        #pragma unroll
        for (int ks = 0; ks < 12; ++ks) {
            const int kg = ks * 32 + q * 8;          // 0..383
            Frag ag;
            ag.u = *(const u16x8*)(&GfS[(kg >> 3) * 128 + m * 8]);
            #pragma unroll
            for (int j = 0; j < 6; ++j) {
                const int tile = (j >> 1) * 8 + wave * 2 + (j & 1);
                Frag bg;
                bg.u = *(const u16x8*)(Bt + (tile * 16 + m) * 384 + kg);
                acc2[j] = __builtin_amdgcn_mfma_f32_16x16x32_bf16(
                    ag.b, bg.b, acc2[j], 0, 0, 0);
            }
        }
    }
    __syncthreads();   // credS ready for all waves

    // ---------- epilogue: straight from acc2 registers ----------
    {
        #pragma unroll
        for (int jj = 0; jj < 2; ++jj) {
            const int c = (wave * 2 + jj) * 16 + m;   // 0..127
            const float bi = biou[c];
            const float bo = biou[128 + c];
            const float bu = biou[256 + c];
            #pragma unroll
            for (int reg = 0; reg < 4; ++reg) {
                const int n = q * 4 + reg;
                const float ii = sigm(acc2[jj][reg] + bi);
                const float oo = sigm(acc2[2 + jj][reg] + bo);
                const float uu = tanhf(acc2[4 + jj][reg] + bu);
                const float cc = ii * uu + credS[n * 132 + c];
                out[(node0 + n) * HH + c] = oo * tanhf(cc);
                out[NN * HH + (node0 + n) * HH + c] = cc;
            }
        }
    }
}

extern "C" void kernel_launch(void* const* d_in, const int* in_sizes, int n_in,
                              void* d_out, int out_size, void* d_ws, size_t ws_size,
                              hipStream_t stream) {
    const float* x      = (const float*)d_in[0];
    const float* h_mail = (const float*)d_in[1];
    const float* c_mail = (const float*)d_in[2];
    const float* Uiou   = (const float*)d_in[4];
    const float* biou   = (const float*)d_in[5];
    const float* Of     = (const float*)d_in[6];
    const float* Zf     = (const float*)d_in[7];
    const float* Qf     = (const float*)d_in[8];
    const float* Kf     = (const float*)d_in[9];
    const float* vf     = (const float*)d_in[10];
    const float* Wa     = (const float*)d_in[11];
    const float* Wd     = (const float*)d_in[12];
    const float* Vf     = (const float*)d_in[13];
    const int*   etype  = (const int*)d_in[14];
    const float* Wiou   = (const float*)d_in[3];
    float* ws  = (float*)d_ws;
    float* out = (float*)d_out;

    hipLaunchKernelGGL(prepA, dim3(385), dim3(256), 0, stream, Kf, Qf, vf, Vf, Wiou, Of, Zf, ws);
    hipLaunchKernelGGL(prep2, dim3(128), dim3(256), 0, stream, Wd, Wa, ws);
    hipLaunchKernelGGL(prep3, dim3(384), dim3(256), 0, stream, Uiou, ws);
    hipLaunchKernelGGL(tree_main, dim3(3125), dim3(256), 0, stream,
                       x, h_mail, c_mail, biou, etype, ws, out);
}